// Round 14
// baseline (28.029 us; speedup 1.0000x reference)
//
#include <hip/hip_runtime.h>

#define NN 20000
#define VV 100000
#define CC 5000
#define MM 32
#define KK 2048
#define DD 128

// ws: active[CC] @0 ; memb @32768 (2.56MB) ; w1f bf16 @2592768 (96KB) ; w3f bf16 @2691072 (16KB)
#define WS_MEMB 32768
#define WS_W1F  2592768
#define WS_W3F  2691072

typedef __attribute__((ext_vector_type(8))) short bf16x8;
typedef __attribute__((ext_vector_type(4))) float f32x4;

__device__ __forceinline__ unsigned f2bf_rne(float f) {  // bf16 in low 16 bits
  unsigned u = __builtin_bit_cast(unsigned, f);
  u += 0x7fffu + ((u >> 16) & 1u);
  return u >> 16;
}

// ---------------- K0: init = zero+scatter (block 0) | W1,W3 -> bf16 FRAGMENT order ------------
// Fragment order: elem (ct, ks, lane, e) at index ((ct*NKS+ks)*64+lane)*8+e holds
// B[k][col] with col = ct*16 + (lane&15), k = ks*32 + (lane>>4)*8 + e.
__global__ __launch_bounds__(256) void init_k(const int* __restrict__ cidx,
    int* __restrict__ active, const float* __restrict__ W1,
    unsigned short* __restrict__ w1f, const float* __restrict__ W3,
    unsigned short* __restrict__ w3f) {
  int b = blockIdx.x, tid = threadIdx.x;
  if (b == 0) {
    for (int i = tid; i < CC; i += 256) active[i] = 0;
    __syncthreads();
    for (int k = tid; k < KK; k += 256) active[cidx[k]] = 1;
  } else if (b <= 192) {
    int i = (b - 1) * 256 + tid;      // 0..49151 ; w1f: 8 ct x 12 ks
    int e = i & 7, slot = i >> 3;
    int lane = slot & 63, g = slot >> 6;   // g = ct*12 + ks
    int ks = g % 12, ct = g / 12;
    int c = ct * 16 + (lane & 15);
    int k = ks * 32 + (lane >> 4) * 8 + e;
    w1f[i] = (unsigned short)f2bf_rne(W1[(size_t)k * DD + c]);
  } else {                              // b == 193 ; w3f: 4 ct x 4 ks = 8192 elems
    for (int i = tid; i < 64 * DD; i += 256) {
      int e = i & 7, slot = i >> 3;
      int lane = slot & 63, g = slot >> 6;  // g = ct*4 + ks
      int ks = g & 3, ct = g >> 2;
      int h = ct * 16 + (lane & 15);
      int k = ks * 32 + (lane >> 4) * 8 + e;
      w3f[i] = (unsigned short)f2bf_rne(W3[(size_t)k * 64 + h]);
    }
  }
}

// ---------------- K1: member embedding, driven by cidx (2048 blocks) ----------------
__global__ __launch_bounds__(128) void member_emb_k(const int* __restrict__ c2n,
    const int* __restrict__ n2c, const float* __restrict__ mscore,
    const int* __restrict__ mnum, const int* __restrict__ active,
    const int* __restrict__ cidx, const float* __restrict__ cemb,
    float* __restrict__ memb) {
  int c = cidx[blockIdx.x];  // active by construction
  __shared__ float s_sc[MM];
  __shared__ int s_nc[MM];
  int t = threadIdx.x;  // 0..127 = d
  if (t < MM) {
    int mem = c2n[c * MM + t];
    int nc = n2c[mem];
    bool valid = (t < mnum[c]) && (active[nc] != 0);
    s_nc[t] = nc;
    s_sc[t] = valid ? mscore[c * MM + t] : 0.f;
  }
  __syncthreads();
  float acc = 0.f;
  #pragma unroll
  for (int m = 0; m < MM; ++m)
    acc = fmaf(s_sc[m], cemb[(size_t)s_nc[m] * DD + t], acc);
  memb[(size_t)c * DD + t] = acc;
}

// ---------------- K2: main = feat stage (frag order) + MFMA (2 row-tiles/block) + select ------
// 512 thr, 32 rows/block (2 row-tiles of 16), 625 blocks. LDS ~25.5 KB -> 4 blocks/CU.
// Each B-fragment loaded ONCE per wave, applied to both row-tiles (halves B L2 traffic).
// A staged in LDS in fragment order (conflict-free lane*16 ds_read_b128).
// Wave w = pred1 col-tile (cols w*16..+15); pred2 tile w&3 (only w<4 writes).
// C/D mapping (verified R6): out_row = rt*16 + (lane>>4)*4 + j, col = tile_base + (lane&15).
__global__ __launch_bounds__(512) void main_k(const float* __restrict__ node_emb,
    const float* __restrict__ cemb, const float* __restrict__ memb,
    const unsigned short* __restrict__ w1f, const float* __restrict__ b1,
    const float* __restrict__ W2, const float* __restrict__ b2v,
    const unsigned short* __restrict__ w3f, const float* __restrict__ b3,
    const float* __restrict__ W4, const float* __restrict__ b4v,
    const int* __restrict__ n2c, const int* __restrict__ active,
    const int* __restrict__ nodes, float* __restrict__ out) {
  __shared__ __align__(16) unsigned short s_hi[2 * 12 * 64 * 8];  // 24 KB, frag order
  __shared__ int s_v[32], s_cm[32], s_use[32];
  __shared__ float s_r1[32][8], s_r2[32][4];
  int tid = threadIdx.x;
  int n0 = blockIdx.x * 32;
  if (tid < 32) {
    int v = nodes[n0 + tid], cm = n2c[v];
    s_v[tid] = v; s_cm[tid] = cm; s_use[tid] = active[cm];
  }
  __syncthreads();
  {  // stage feat bf16 into FRAGMENT order: 32 rows x 96 float4, 6 per thread
    #pragma unroll
    for (int it = 0; it < 6; ++it) {
      int i4 = it * 512 + tid;
      int row = i4 / 96, pos = i4 % 96;
      int off = pos * 4;                      // feat column base, off%8 in {0,4}
      int use = s_use[row];
      float4 f;
      if (off < DD) {
        f = *(const float4*)(node_emb + (size_t)(n0 + row) * DD + off);
      } else if (off < 2 * DD) {
        f = use ? *(const float4*)(cemb + (size_t)s_v[row] * DD + (off - DD))
                : make_float4(0.f, 0.f, 0.f, 0.f);
      } else {
        f = use ? *(const float4*)(memb + (size_t)s_cm[row] * DD + (off - 2 * DD))
                : make_float4(0.f, 0.f, 0.f, 0.f);
      }
      unsigned h0 = f2bf_rne(f.x), h1 = f2bf_rne(f.y),
               h2 = f2bf_rne(f.z), h3 = f2bf_rne(f.w);
      // frag index: tile rt=row>>4; ks = off>>5; lane_slot = (row&15) + 16*((off>>3)&3)
      int rt = row >> 4, r16 = row & 15;
      int base = rt * 6144
               + (((off >> 5) * 64) + r16 + 16 * ((off >> 3) & 3)) * 8 + (off & 7);
      *(uint2*)&s_hi[base] = make_uint2(h0 | (h1 << 16), h2 | (h3 << 16));
    }
  }
  __syncthreads();
  int lane = tid & 63, w = tid >> 6;
  int lrow = lane & 15, lkq = lane >> 4;
  const bf16x8* ahf = (const bf16x8*)s_hi;             // [2][12][64]
  const bf16x8* b1f = (const bf16x8*)w1f + (size_t)w * 12 * 64 + lane;
  const bf16x8* b3f = (const bf16x8*)w3f + (size_t)(w & 3) * 4 * 64 + lane;
  f32x4 acc[2] = {{0.f, 0.f, 0.f, 0.f}, {0.f, 0.f, 0.f, 0.f}};
  f32x4 p2[2]  = {{0.f, 0.f, 0.f, 0.f}, {0.f, 0.f, 0.f, 0.f}};
  #pragma unroll
  for (int ks = 0; ks < 4; ++ks) {  // pred1 + pred2 share A-frags (k < 128)
    bf16x8 va0 = ahf[ks * 64 + lane];
    bf16x8 va1 = ahf[768 + ks * 64 + lane];
    bf16x8 vb0 = b1f[ks * 64];
    bf16x8 vb2 = b3f[ks * 64];
    acc[0] = __builtin_amdgcn_mfma_f32_16x16x32_bf16(va0, vb0, acc[0], 0, 0, 0);
    acc[1] = __builtin_amdgcn_mfma_f32_16x16x32_bf16(va1, vb0, acc[1], 0, 0, 0);
    p2[0]  = __builtin_amdgcn_mfma_f32_16x16x32_bf16(va0, vb2, p2[0], 0, 0, 0);
    p2[1]  = __builtin_amdgcn_mfma_f32_16x16x32_bf16(va1, vb2, p2[1], 0, 0, 0);
  }
  #pragma unroll
  for (int ks = 4; ks < 12; ++ks) {  // pred1 only
    bf16x8 va0 = ahf[ks * 64 + lane];
    bf16x8 va1 = ahf[768 + ks * 64 + lane];
    bf16x8 vb0 = b1f[ks * 64];
    acc[0] = __builtin_amdgcn_mfma_f32_16x16x32_bf16(va0, vb0, acc[0], 0, 0, 0);
    acc[1] = __builtin_amdgcn_mfma_f32_16x16x32_bf16(va1, vb0, acc[1], 0, 0, 0);
  }
  {  // pred1 epilogue: reduce 16 cols of tile w, both row-tiles
    int c0 = w * 16 + lrow;
    float b1a = b1[c0], w2a = W2[c0];
    #pragma unroll
    for (int rt = 0; rt < 2; ++rt) {
      float vsum[4];
      #pragma unroll
      for (int j = 0; j < 4; ++j) vsum[j] = fmaxf(acc[rt][j] + b1a, 0.f) * w2a;
      #pragma unroll
      for (int m = 1; m <= 8; m <<= 1)
        #pragma unroll
        for (int j = 0; j < 4; ++j) vsum[j] += __shfl_xor(vsum[j], m, 64);
      if (lrow == 0) {
        #pragma unroll
        for (int j = 0; j < 4; ++j) s_r1[rt * 16 + lkq * 4 + j][w] = vsum[j];
      }
    }
  }
  {  // pred2 epilogue (waves 0-3 write)
    int h = (w & 3) * 16 + lrow;
    float b3v = b3[h], w4v = W4[h];
    #pragma unroll
    for (int rt = 0; rt < 2; ++rt) {
      float q[4];
      #pragma unroll
      for (int j = 0; j < 4; ++j) q[j] = fmaxf(p2[rt][j] + b3v, 0.f) * w4v;
      #pragma unroll
      for (int m = 1; m <= 8; m <<= 1)
        #pragma unroll
        for (int j = 0; j < 4; ++j) q[j] += __shfl_xor(q[j], m, 64);
      if (lrow == 0 && w < 4) {
        #pragma unroll
        for (int j = 0; j < 4; ++j) s_r2[rt * 16 + lkq * 4 + j][w] = q[j];
      }
    }
  }
  __syncthreads();
  if (tid < 32) {
    float r;
    if (s_use[tid]) {
      r = b2v[0];
      #pragma unroll
      for (int c = 0; c < 8; ++c) r += s_r1[tid][c];
    } else {
      r = s_r2[tid][0] + s_r2[tid][1] + s_r2[tid][2] + s_r2[tid][3] + b4v[0];
    }
    out[n0 + tid] = r;
  }
}

extern "C" void kernel_launch(void* const* d_in, const int* in_sizes, int n_in,
                              void* d_out, int out_size, void* d_ws, size_t ws_size,
                              hipStream_t stream) {
  const float* node_emb = (const float*)d_in[0];
  const float* mscore   = (const float*)d_in[1];
  const float* cemb     = (const float*)d_in[2];
  const float* W1 = (const float*)d_in[3];
  const float* b1 = (const float*)d_in[4];
  const float* W2 = (const float*)d_in[5];
  const float* b2 = (const float*)d_in[6];
  const float* W3 = (const float*)d_in[7];
  const float* b3 = (const float*)d_in[8];
  const float* W4 = (const float*)d_in[9];
  const float* b4 = (const float*)d_in[10];
  const int* n2c   = (const int*)d_in[11];
  const int* c2n   = (const int*)d_in[12];
  const int* mnum  = (const int*)d_in[13];
  const int* cidx  = (const int*)d_in[14];
  const int* nodes = (const int*)d_in[15];
  float* out = (float*)d_out;

  int* active = (int*)d_ws;
  float* memb = (float*)((char*)d_ws + WS_MEMB);
  unsigned short* w1f = (unsigned short*)((char*)d_ws + WS_W1F);
  unsigned short* w3f = (unsigned short*)((char*)d_ws + WS_W3F);

  init_k<<<194, 256, 0, stream>>>(cidx, active, W1, w1f, W3, w3f);
  member_emb_k<<<KK, 128, 0, stream>>>(c2n, n2c, mscore, mnum, active, cidx,
                                       cemb, memb);
  main_k<<<NN / 32, 512, 0, stream>>>(node_emb, cemb, memb, w1f, b1, W2, b2,
                                      w3f, b3, W4, b4, n2c, active, nodes, out);
}

// Round 15
// 27.086 us; speedup vs baseline: 1.0348x; 1.0348x over previous
//
#include <hip/hip_runtime.h>

#define NN 20000
#define VV 100000
#define CC 5000
#define MM 32
#define KK 2048
#define DD 128

// ws: active[CC] @0 ; memb @32768 (2.56MB) ; w1f bf16 @2592768 (96KB) ; w3f bf16 @2691072 (16KB)
#define WS_MEMB 32768
#define WS_W1F  2592768
#define WS_W3F  2691072

typedef __attribute__((ext_vector_type(8))) short bf16x8;
typedef __attribute__((ext_vector_type(4))) float f32x4;

__device__ __forceinline__ unsigned f2bf_rne(float f) {  // bf16 in low 16 bits
  unsigned u = __builtin_bit_cast(unsigned, f);
  u += 0x7fffu + ((u >> 16) & 1u);
  return u >> 16;
}

// ---------------- K0: init = zero+scatter (block 0) | W1,W3 -> bf16 FRAGMENT order ------------
__global__ __launch_bounds__(256) void init_k(const int* __restrict__ cidx,
    int* __restrict__ active, const float* __restrict__ W1,
    unsigned short* __restrict__ w1f, const float* __restrict__ W3,
    unsigned short* __restrict__ w3f) {
  int b = blockIdx.x, tid = threadIdx.x;
  if (b == 0) {
    for (int i = tid; i < CC; i += 256) active[i] = 0;
    __syncthreads();
    for (int k = tid; k < KK; k += 256) active[cidx[k]] = 1;
  } else if (b <= 192) {
    int i = (b - 1) * 256 + tid;      // 0..49151 ; w1f: 8 ct x 12 ks
    int e = i & 7, slot = i >> 3;
    int lane = slot & 63, g = slot >> 6;   // g = ct*12 + ks
    int ks = g % 12, ct = g / 12;
    int c = ct * 16 + (lane & 15);
    int k = ks * 32 + (lane >> 4) * 8 + e;
    w1f[i] = (unsigned short)f2bf_rne(W1[(size_t)k * DD + c]);
  } else {                              // b == 193 ; w3f: 4 ct x 4 ks = 8192 elems
    for (int i = tid; i < 64 * DD; i += 256) {
      int e = i & 7, slot = i >> 3;
      int lane = slot & 63, g = slot >> 6;  // g = ct*4 + ks
      int ks = g & 3, ct = g >> 2;
      int h = ct * 16 + (lane & 15);
      int k = ks * 32 + (lane >> 4) * 8 + e;
      w3f[i] = (unsigned short)f2bf_rne(W3[(size_t)k * 64 + h]);
    }
  }
}

// ---------------- K1: member embedding, driven by cidx (2048 blocks) ----------------
// (128,4): allow ~128 VGPRs so the 32 cemb gathers stay in flight; 4-way acc split.
__global__ __launch_bounds__(128, 4) void member_emb_k(const int* __restrict__ c2n,
    const int* __restrict__ n2c, const float* __restrict__ mscore,
    const int* __restrict__ mnum, const int* __restrict__ active,
    const int* __restrict__ cidx, const float* __restrict__ cemb,
    float* __restrict__ memb) {
  int c = cidx[blockIdx.x];  // active by construction
  __shared__ float s_sc[MM];
  __shared__ int s_nc[MM];
  int t = threadIdx.x;  // 0..127 = d
  if (t < MM) {
    int mem = c2n[c * MM + t];
    int nc = n2c[mem];
    bool valid = (t < mnum[c]) && (active[nc] != 0);
    s_nc[t] = nc;
    s_sc[t] = valid ? mscore[c * MM + t] : 0.f;
  }
  __syncthreads();
  float a0 = 0.f, a1 = 0.f, a2 = 0.f, a3 = 0.f;
  #pragma unroll
  for (int m = 0; m < MM; m += 4) {  // 4 independent chains, loads pipelined
    a0 = fmaf(s_sc[m + 0], cemb[(size_t)s_nc[m + 0] * DD + t], a0);
    a1 = fmaf(s_sc[m + 1], cemb[(size_t)s_nc[m + 1] * DD + t], a1);
    a2 = fmaf(s_sc[m + 2], cemb[(size_t)s_nc[m + 2] * DD + t], a2);
    a3 = fmaf(s_sc[m + 3], cemb[(size_t)s_nc[m + 3] * DD + t], a3);
  }
  memb[(size_t)c * DD + t] = ((a0 + a1) + (a2 + a3));
}

// ---------------- K2: main = feat stage (issue-early) + MFMA (2 row-tiles) + select ----------
// 512 thr, 32 rows/block, 625 blocks. LDS ~25.5 KB. (512,4): <=128 VGPRs, 2 blocks/CU.
// Stage: issue ALL 6 float4 loads first (T14 issue-early), then convert+write.
// A staged in LDS in fragment order; B from global w1f/w3f in fragment order.
// C/D mapping (verified R6): out_row = rt*16 + (lane>>4)*4 + j, col = tile_base + (lane&15).
__global__ __launch_bounds__(512, 4) void main_k(const float* __restrict__ node_emb,
    const float* __restrict__ cemb, const float* __restrict__ memb,
    const unsigned short* __restrict__ w1f, const float* __restrict__ b1,
    const float* __restrict__ W2, const float* __restrict__ b2v,
    const unsigned short* __restrict__ w3f, const float* __restrict__ b3,
    const float* __restrict__ W4, const float* __restrict__ b4v,
    const int* __restrict__ n2c, const int* __restrict__ active,
    const int* __restrict__ nodes, float* __restrict__ out) {
  __shared__ __align__(16) unsigned short s_hi[2 * 12 * 64 * 8];  // 24 KB, frag order
  __shared__ int s_v[32], s_cm[32], s_use[32];
  __shared__ float s_r1[32][8], s_r2[32][4];
  int tid = threadIdx.x;
  int n0 = blockIdx.x * 32;
  if (tid < 32) {
    int v = nodes[n0 + tid], cm = n2c[v];
    s_v[tid] = v; s_cm[tid] = cm; s_use[tid] = active[cm];
  }
  __syncthreads();
  {  // stage feat bf16 into FRAGMENT order: issue all loads, then convert+write
    float4 f[6];
    int baseidx[6];
    #pragma unroll
    for (int it = 0; it < 6; ++it) {
      int i4 = it * 512 + tid;
      int row = i4 / 96, pos = i4 % 96;
      int off = pos * 4;
      int use = s_use[row];
      const float* src;
      bool live = true;
      if (off < DD) {
        src = node_emb + (size_t)(n0 + row) * DD + off;
      } else if (off < 2 * DD) {
        src = cemb + (size_t)s_v[row] * DD + (off - DD);
        live = use != 0;
      } else {
        src = memb + (size_t)s_cm[row] * DD + (off - 2 * DD);
        live = use != 0;
      }
      f[it] = live ? *(const float4*)src : make_float4(0.f, 0.f, 0.f, 0.f);
      int rt = row >> 4, r16 = row & 15;
      baseidx[it] = rt * 6144
                  + (((off >> 5) * 64) + r16 + 16 * ((off >> 3) & 3)) * 8 + (off & 7);
    }
    #pragma unroll
    for (int it = 0; it < 6; ++it) {
      unsigned h0 = f2bf_rne(f[it].x), h1 = f2bf_rne(f[it].y),
               h2 = f2bf_rne(f[it].z), h3 = f2bf_rne(f[it].w);
      *(uint2*)&s_hi[baseidx[it]] = make_uint2(h0 | (h1 << 16), h2 | (h3 << 16));
    }
  }
  __syncthreads();
  int lane = tid & 63, w = tid >> 6;
  int lrow = lane & 15, lkq = lane >> 4;
  const bf16x8* ahf = (const bf16x8*)s_hi;             // [2][12][64]
  const bf16x8* b1f = (const bf16x8*)w1f + (size_t)w * 12 * 64 + lane;
  const bf16x8* b3f = (const bf16x8*)w3f + (size_t)(w & 3) * 4 * 64 + lane;
  f32x4 acc[2] = {{0.f, 0.f, 0.f, 0.f}, {0.f, 0.f, 0.f, 0.f}};
  f32x4 p2[2]  = {{0.f, 0.f, 0.f, 0.f}, {0.f, 0.f, 0.f, 0.f}};
  #pragma unroll
  for (int ks = 0; ks < 4; ++ks) {  // pred1 + pred2 share A-frags (k < 128)
    bf16x8 va0 = ahf[ks * 64 + lane];
    bf16x8 va1 = ahf[768 + ks * 64 + lane];
    bf16x8 vb0 = b1f[ks * 64];
    bf16x8 vb2 = b3f[ks * 64];
    acc[0] = __builtin_amdgcn_mfma_f32_16x16x32_bf16(va0, vb0, acc[0], 0, 0, 0);
    acc[1] = __builtin_amdgcn_mfma_f32_16x16x32_bf16(va1, vb0, acc[1], 0, 0, 0);
    p2[0]  = __builtin_amdgcn_mfma_f32_16x16x32_bf16(va0, vb2, p2[0], 0, 0, 0);
    p2[1]  = __builtin_amdgcn_mfma_f32_16x16x32_bf16(va1, vb2, p2[1], 0, 0, 0);
  }
  #pragma unroll
  for (int ks = 4; ks < 12; ++ks) {  // pred1 only
    bf16x8 va0 = ahf[ks * 64 + lane];
    bf16x8 va1 = ahf[768 + ks * 64 + lane];
    bf16x8 vb0 = b1f[ks * 64];
    acc[0] = __builtin_amdgcn_mfma_f32_16x16x32_bf16(va0, vb0, acc[0], 0, 0, 0);
    acc[1] = __builtin_amdgcn_mfma_f32_16x16x32_bf16(va1, vb0, acc[1], 0, 0, 0);
  }
  {  // pred1 epilogue: reduce 16 cols of tile w, both row-tiles
    int c0 = w * 16 + lrow;
    float b1a = b1[c0], w2a = W2[c0];
    #pragma unroll
    for (int rt = 0; rt < 2; ++rt) {
      float vsum[4];
      #pragma unroll
      for (int j = 0; j < 4; ++j) vsum[j] = fmaxf(acc[rt][j] + b1a, 0.f) * w2a;
      #pragma unroll
      for (int m = 1; m <= 8; m <<= 1)
        #pragma unroll
        for (int j = 0; j < 4; ++j) vsum[j] += __shfl_xor(vsum[j], m, 64);
      if (lrow == 0) {
        #pragma unroll
        for (int j = 0; j < 4; ++j) s_r1[rt * 16 + lkq * 4 + j][w] = vsum[j];
      }
    }
  }
  {  // pred2 epilogue (waves 0-3 write)
    int h = (w & 3) * 16 + lrow;
    float b3v = b3[h], w4v = W4[h];
    #pragma unroll
    for (int rt = 0; rt < 2; ++rt) {
      float q[4];
      #pragma unroll
      for (int j = 0; j < 4; ++j) q[j] = fmaxf(p2[rt][j] + b3v, 0.f) * w4v;
      #pragma unroll
      for (int m = 1; m <= 8; m <<= 1)
        #pragma unroll
        for (int j = 0; j < 4; ++j) q[j] += __shfl_xor(q[j], m, 64);
      if (lrow == 0 && w < 4) {
        #pragma unroll
        for (int j = 0; j < 4; ++j) s_r2[rt * 16 + lkq * 4 + j][w] = q[j];
      }
    }
  }
  __syncthreads();
  if (tid < 32) {
    float r;
    if (s_use[tid]) {
      r = b2v[0];
      #pragma unroll
      for (int c = 0; c < 8; ++c) r += s_r1[tid][c];
    } else {
      r = s_r2[tid][0] + s_r2[tid][1] + s_r2[tid][2] + s_r2[tid][3] + b4v[0];
    }
    out[n0 + tid] = r;
  }
}

extern "C" void kernel_launch(void* const* d_in, const int* in_sizes, int n_in,
                              void* d_out, int out_size, void* d_ws, size_t ws_size,
                              hipStream_t stream) {
  const float* node_emb = (const float*)d_in[0];
  const float* mscore   = (const float*)d_in[1];
  const float* cemb     = (const float*)d_in[2];
  const float* W1 = (const float*)d_in[3];
  const float* b1 = (const float*)d_in[4];
  const float* W2 = (const float*)d_in[5];
  const float* b2 = (const float*)d_in[6];
  const float* W3 = (const float*)d_in[7];
  const float* b3 = (const float*)d_in[8];
  const float* W4 = (const float*)d_in[9];
  const float* b4 = (const float*)d_in[10];
  const int* n2c   = (const int*)d_in[11];
  const int* c2n   = (const int*)d_in[12];
  const int* mnum  = (const int*)d_in[13];
  const int* cidx  = (const int*)d_in[14];
  const int* nodes = (const int*)d_in[15];
  float* out = (float*)d_out;

  int* active = (int*)d_ws;
  float* memb = (float*)((char*)d_ws + WS_MEMB);
  unsigned short* w1f = (unsigned short*)((char*)d_ws + WS_W1F);
  unsigned short* w3f = (unsigned short*)((char*)d_ws + WS_W3F);

  init_k<<<194, 256, 0, stream>>>(cidx, active, W1, w1f, W3, w3f);
  member_emb_k<<<KK, 128, 0, stream>>>(c2n, n2c, mscore, mnum, active, cidx,
                                       cemb, memb);
  main_k<<<NN / 32, 512, 0, stream>>>(node_emb, cemb, memb, w1f, b1, W2, b2,
                                      w3f, b3, W4, b4, n2c, active, nodes, out);
}